// Round 14
// baseline (78.700 us; speedup 1.0000x reference)
//
#include <hip/hip_runtime.h>

#define T_ 500
#define R_ 50
#define NS_ 1000
#define H1_ 32
#define H2_ 16
#define NEG_ 0.2f
#define NROWS_ (NS_ * R_)   // 50000
#define TROWS_ 16           // gu rows staged per block (32000 B LDS)

__device__ __forceinline__ float lrelu(float x) { return x >= 0.f ? x : NEG_ * x; }

// Full-wave (64 lane) sum via DPP: row_shr 1/2/4/8, row_bcast:15, row_bcast:31.
__device__ __forceinline__ float wave_sum_dpp(float x) {
    int t;
    t = __builtin_amdgcn_update_dpp(0, __float_as_int(x), 0x111, 0xf, 0xf, true);
    x += __int_as_float(t);
    t = __builtin_amdgcn_update_dpp(0, __float_as_int(x), 0x112, 0xf, 0xf, true);
    x += __int_as_float(t);
    t = __builtin_amdgcn_update_dpp(0, __float_as_int(x), 0x114, 0xf, 0xf, true);
    x += __int_as_float(t);
    t = __builtin_amdgcn_update_dpp(0, __float_as_int(x), 0x118, 0xf, 0xf, true);
    x += __int_as_float(t);
    t = __builtin_amdgcn_update_dpp(0, __float_as_int(x), 0x142, 0xf, 0xf, true);
    x += __int_as_float(t);
    t = __builtin_amdgcn_update_dpp(0, __float_as_int(x), 0x143, 0xf, 0xf, true);
    x += __int_as_float(t);
    return __int_as_float(__builtin_amdgcn_readlane(__float_as_int(x), 63));
}

// One block per t: y1[t][c] = sum_f x[t][f] * gc1_w[f][c]
__global__ __launch_bounds__(256) void k1_xw(const float* __restrict__ state,
                                             const float* __restrict__ payoff,
                                             const float* __restrict__ noise,
                                             const float* __restrict__ w,
                                             float* __restrict__ y1) {
    __shared__ float xs[504];
    __shared__ float red[8][H1_];
    int t = blockIdx.x, tid = threadIdx.x;
    for (int u = tid; u < T_; u += 256) xs[2 + u] = payoff[t * T_ + u];
    if (tid == 0) {
        xs[0] = state[t * 2];     xs[1] = state[t * 2 + 1];
        xs[502] = noise[t * 2];   xs[503] = noise[t * 2 + 1];
    }
    __syncthreads();
    int c = tid & 31, kg = tid >> 5;
    float acc = 0.f;
#pragma unroll 7
    for (int f = kg; f < 504; f += 8) acc += xs[f] * w[f * H1_ + c];
    red[kg][c] = acc;
    __syncthreads();
    if (tid < H1_) {
        float a = 0.f;
#pragma unroll
        for (int s = 0; s < 8; ++s) a += red[s][tid];
        y1[t * H1_ + tid] = a;
    }
}

// One block per t: h1row = lrelu(bn(adj[t]@y1 + b)); y2[t][c2] = h1row @ g2w
__global__ __launch_bounds__(256) void k2_adj_fused(const float* __restrict__ adj,
                                                    const float* __restrict__ y1,
                                                    const float* __restrict__ b,
                                                    const float* __restrict__ gamma,
                                                    const float* __restrict__ beta,
                                                    const float* __restrict__ w2,
                                                    float* __restrict__ y2) {
    __shared__ float arow[T_];
    __shared__ float red[8][H1_];
    __shared__ float h1row[H1_];
    int t = blockIdx.x, tid = threadIdx.x;
    for (int u = tid; u < T_; u += 256) arow[u] = adj[t * T_ + u];
    __syncthreads();
    int c = tid & 31, kg = tid >> 5;
    float acc = 0.f;
#pragma unroll 4
    for (int u = kg; u < T_; u += 8) acc += arow[u] * y1[u * H1_ + c];
    red[kg][c] = acc;
    __syncthreads();
    if (tid < H1_) {
        float a = 0.f;
#pragma unroll
        for (int s = 0; s < 8; ++s) a += red[s][tid];
        h1row[tid] = lrelu((a + b[tid]) * gamma[t] + beta[t]);
    }
    __syncthreads();
    if (tid < H2_) {
        float a = 0.f;
#pragma unroll
        for (int cc = 0; cc < H1_; ++cc) a += h1row[cc] * w2[cc * H2_ + tid];
        y2[t * H2_ + tid] = a;
    }
}

// One block per t: xfrow = lrelu(bn(adj[t]@y2 + b2)); part1[t][j] = xfrow @ aw rows
__global__ __launch_bounds__(256) void k3_adj2_aw(const float* __restrict__ adj,
                                                  const float* __restrict__ y2,
                                                  const float* __restrict__ b2,
                                                  const float* __restrict__ gamma,
                                                  const float* __restrict__ beta,
                                                  const float* __restrict__ aw,
                                                  float* __restrict__ part1) {
    __shared__ float arow[T_];
    __shared__ float red[16][H2_];
    __shared__ float xfr[H2_];
    int t = blockIdx.x, tid = threadIdx.x;
    for (int u = tid; u < T_; u += 256) arow[u] = adj[t * T_ + u];
    __syncthreads();
    int c2 = tid & 15, kg = tid >> 4;
    float acc = 0.f;
#pragma unroll 4
    for (int u = kg; u < T_; u += 16) acc += arow[u] * y2[u * H2_ + c2];
    red[kg][c2] = acc;
    __syncthreads();
    if (tid < H2_) {
        float a = 0.f;
#pragma unroll
        for (int s = 0; s < 16; ++s) a += red[s][tid];
        xfr[tid] = lrelu((a + b2[tid]) * gamma[t] + beta[t]);
    }
    __syncthreads();
    float acc0 = 0.f, acc1 = 0.f;
#pragma unroll
    for (int c = 0; c < H2_; ++c) {
        float xv = xfr[c];
        const float* awr = aw + (t * H2_ + c) * T_;
        acc0 += xv * awr[tid];
        if (tid < T_ - 256) acc1 += xv * awr[256 + tid];
    }
    part1[t * T_ + tid] = acc0;
    if (tid < T_ - 256) part1[t * T_ + 256 + tid] = acc1;
}

// part2[q][r*T+j] = sum_{t in quarter q} dloc[r][t]*av[t][j] + part1[t][j]
__global__ __launch_bounds__(256) void k4_logits_part(const float* __restrict__ dloc,
                                                      const float* __restrict__ av,
                                                      const float* __restrict__ part1,
                                                      float* __restrict__ part2) {
    int r = blockIdx.x;
    int jb = blockIdx.y & 1, q = blockIdx.y >> 1;
    __shared__ float drow[125];
    int tid = threadIdx.x;
    int t0 = q * 125;
    if (tid < 125) drow[tid] = dloc[r * T_ + t0 + tid];
    __syncthreads();
    if (tid >= 250) return;
    int j = jb * 250 + tid;
    float acc = 0.f;
#pragma unroll 5
    for (int i = 0; i < 125; ++i) {
        int t = t0 + i;
        acc += drow[i] * av[t * T_ + j] + part1[t * T_ + j];
    }
    part2[q * (R_ * T_) + r * T_ + j] = acc;
}

// elog[x] = exp(sum_q part2[q][x])
__global__ __launch_bounds__(256) void k4_reduce_exp(const float* __restrict__ part2,
                                                     float* __restrict__ elog) {
    int gid = blockIdx.x * 256 + threadIdx.x;
    if (gid >= R_ * T_) return;
    float v = part2[gid] + part2[R_ * T_ + gid] +
              part2[2 * R_ * T_ + gid] + part2[3 * R_ * T_ + gid];
    elog[gid] = __expf(v);
}

// Block stages 16 contiguous gu rows (32KB) into LDS via global_load_lds DMA
// (no VGPR round-trip, regalloc cannot sink it). Each wave: issue 8 DMA ops ->
// vmcnt(0) -> process its 4 rows from LDS. ~160KB/CU in flight at 5 blocks/CU.
// softmax identity: softmax(logit - log(-log u)) = elog * rcp(-log2 u) / rowsum.
typedef const char __attribute__((address_space(1)))* gas_p;
typedef char __attribute__((address_space(3)))* las_p;

__global__ __launch_bounds__(256) void k7_softmax(const float* __restrict__ gu,
                                                  const float4* __restrict__ elog,
                                                  float4* __restrict__ out) {
    __shared__ char sm[TROWS_ * 2000];
    int b = blockIdx.x;                  // < 3125
    int tid = threadIdx.x;
    int wave = tid >> 6, lane = tid & 63;
    int rbase = b * TROWS_ + wave * 4;   // this wave's 4 rows
    bool has1 = lane < 61;

    const char* gbase = (const char*)gu;
#pragma unroll
    for (int j = 0; j < 4; ++j) {
        size_t goff = (size_t)(rbase + j) * 2000;
        int loff = (wave * 4 + j) * 2000;
        __builtin_amdgcn_global_load_lds((gas_p)(gbase + goff) + lane * 16,
                                         (las_p)(sm + loff), 16, 0, 0);
        if (has1)
            __builtin_amdgcn_global_load_lds((gas_p)(gbase + goff + 1024) + lane * 16,
                                             (las_p)(sm + loff + 1024), 16, 0, 0);
    }
    asm volatile("s_waitcnt vmcnt(0)" ::: "memory");  // this wave's DMA done

#pragma unroll
    for (int j = 0; j < 4; ++j) {
        int row = rbase + j;
        const float4* lrow = (const float4*)(sm + (wave * 4 + j) * 2000);
        float4 g0 = lrow[lane];
        float4 g1 = has1 ? lrow[64 + lane] : g0;
        const float4* ep = elog + (row % R_) * 125;
        float4 e0 = ep[lane];
        float4 e1 = has1 ? ep[64 + lane] : e0;

        float p0 = e0.x * __builtin_amdgcn_rcpf(-__log2f(g0.x));
        float p1 = e0.y * __builtin_amdgcn_rcpf(-__log2f(g0.y));
        float p2 = e0.z * __builtin_amdgcn_rcpf(-__log2f(g0.z));
        float p3 = e0.w * __builtin_amdgcn_rcpf(-__log2f(g0.w));
        float p4 = 0.f, p5 = 0.f, p6 = 0.f, p7 = 0.f;
        if (has1) {
            p4 = e1.x * __builtin_amdgcn_rcpf(-__log2f(g1.x));
            p5 = e1.y * __builtin_amdgcn_rcpf(-__log2f(g1.y));
            p6 = e1.z * __builtin_amdgcn_rcpf(-__log2f(g1.z));
            p7 = e1.w * __builtin_amdgcn_rcpf(-__log2f(g1.w));
        }
        float s = ((p0 + p1) + (p2 + p3)) + ((p4 + p5) + (p6 + p7));
        float tot = wave_sum_dpp(s);
        float inv = __builtin_amdgcn_rcpf(tot);

        float4* orow = out + (size_t)row * 125;
        float4 o0 = {p0 * inv, p1 * inv, p2 * inv, p3 * inv};
        orow[lane] = o0;
        if (has1) {
            float4 o1 = {p4 * inv, p5 * inv, p6 * inv, p7 * inv};
            orow[64 + lane] = o1;
        }
    }
}

extern "C" void kernel_launch(void* const* d_in, const int* in_sizes, int n_in,
                              void* d_out, int out_size, void* d_ws, size_t ws_size,
                              hipStream_t stream) {
    const float* state  = (const float*)d_in[0];
    const float* dloc   = (const float*)d_in[1];
    const float* noise  = (const float*)d_in[2];
    const float* gu     = (const float*)d_in[3];
    const float* payoff = (const float*)d_in[4];
    const float* adj    = (const float*)d_in[5];
    const float* g1w    = (const float*)d_in[6];
    const float* g1b    = (const float*)d_in[7];
    const float* g2w    = (const float*)d_in[8];
    const float* g2b    = (const float*)d_in[9];
    const float* gamma  = (const float*)d_in[10];
    const float* beta   = (const float*)d_in[11];
    const float* aw     = (const float*)d_in[12];
    const float* av     = (const float*)d_in[13];
    float* out = (float*)d_out;

    float* ws     = (float*)d_ws;
    float* y1     = ws;           // 16000
    float* y2     = ws + 16000;   // 8000
    float* part1  = ws + 24000;   // 500*500 = 250000
    float* part2  = ws + 274000;  // 4*25000 = 100000
    float* elog   = ws + 374000;  // 25000   (total 399000 floats = 1.6 MB)

    k1_xw<<<T_, 256, 0, stream>>>(state, payoff, noise, g1w, y1);
    k2_adj_fused<<<T_, 256, 0, stream>>>(adj, y1, g1b, gamma, beta, g2w, y2);
    k3_adj2_aw<<<T_, 256, 0, stream>>>(adj, y2, g2b, gamma, beta, aw, part1);
    k4_logits_part<<<dim3(R_, 8), 256, 0, stream>>>(dloc, av, part1, part2);
    k4_reduce_exp<<<(R_ * T_ + 255) / 256, 256, 0, stream>>>(part2, elog);
    k7_softmax<<<NROWS_ / TROWS_, 256, 0, stream>>>(
        gu, (const float4*)elog, (float4*)out);
}

// Round 15
// 73.967 us; speedup vs baseline: 1.0640x; 1.0640x over previous
//
#include <hip/hip_runtime.h>

#define T_ 500
#define R_ 50
#define NS_ 1000
#define H1_ 32
#define H2_ 16
#define NEG_ 0.2f
#define NROWS_ (NS_ * R_)   // 50000
#define NSLOT_ 6250         // 50 r * 125 chunks; each slot = 8 rows

__device__ __forceinline__ float lrelu(float x) { return x >= 0.f ? x : NEG_ * x; }

__device__ __forceinline__ float wave_sum_dpp(float x) {
    int t;
    t = __builtin_amdgcn_update_dpp(0, __float_as_int(x), 0x111, 0xf, 0xf, true);
    x += __int_as_float(t);
    t = __builtin_amdgcn_update_dpp(0, __float_as_int(x), 0x112, 0xf, 0xf, true);
    x += __int_as_float(t);
    t = __builtin_amdgcn_update_dpp(0, __float_as_int(x), 0x114, 0xf, 0xf, true);
    x += __int_as_float(t);
    t = __builtin_amdgcn_update_dpp(0, __float_as_int(x), 0x118, 0xf, 0xf, true);
    x += __int_as_float(t);
    t = __builtin_amdgcn_update_dpp(0, __float_as_int(x), 0x142, 0xf, 0xf, true);
    x += __int_as_float(t);
    t = __builtin_amdgcn_update_dpp(0, __float_as_int(x), 0x143, 0xf, 0xf, true);
    x += __int_as_float(t);
    return __int_as_float(__builtin_amdgcn_readlane(__float_as_int(x), 63));
}

// ---------------- logits chain (unchanged) ----------------
__global__ __launch_bounds__(256) void k1_xw(const float* __restrict__ state,
                                             const float* __restrict__ payoff,
                                             const float* __restrict__ noise,
                                             const float* __restrict__ w,
                                             float* __restrict__ y1) {
    __shared__ float xs[504];
    __shared__ float red[8][H1_];
    int t = blockIdx.x, tid = threadIdx.x;
    for (int u = tid; u < T_; u += 256) xs[2 + u] = payoff[t * T_ + u];
    if (tid == 0) {
        xs[0] = state[t * 2];     xs[1] = state[t * 2 + 1];
        xs[502] = noise[t * 2];   xs[503] = noise[t * 2 + 1];
    }
    __syncthreads();
    int c = tid & 31, kg = tid >> 5;
    float acc = 0.f;
#pragma unroll 7
    for (int f = kg; f < 504; f += 8) acc += xs[f] * w[f * H1_ + c];
    red[kg][c] = acc;
    __syncthreads();
    if (tid < H1_) {
        float a = 0.f;
#pragma unroll
        for (int s = 0; s < 8; ++s) a += red[s][tid];
        y1[t * H1_ + tid] = a;
    }
}

__global__ __launch_bounds__(256) void k2_adj_fused(const float* __restrict__ adj,
                                                    const float* __restrict__ y1,
                                                    const float* __restrict__ b,
                                                    const float* __restrict__ gamma,
                                                    const float* __restrict__ beta,
                                                    const float* __restrict__ w2,
                                                    float* __restrict__ y2) {
    __shared__ float arow[T_];
    __shared__ float red[8][H1_];
    __shared__ float h1row[H1_];
    int t = blockIdx.x, tid = threadIdx.x;
    for (int u = tid; u < T_; u += 256) arow[u] = adj[t * T_ + u];
    __syncthreads();
    int c = tid & 31, kg = tid >> 5;
    float acc = 0.f;
#pragma unroll 4
    for (int u = kg; u < T_; u += 8) acc += arow[u] * y1[u * H1_ + c];
    red[kg][c] = acc;
    __syncthreads();
    if (tid < H1_) {
        float a = 0.f;
#pragma unroll
        for (int s = 0; s < 8; ++s) a += red[s][tid];
        h1row[tid] = lrelu((a + b[tid]) * gamma[t] + beta[t]);
    }
    __syncthreads();
    if (tid < H2_) {
        float a = 0.f;
#pragma unroll
        for (int cc = 0; cc < H1_; ++cc) a += h1row[cc] * w2[cc * H2_ + tid];
        y2[t * H2_ + tid] = a;
    }
}

__global__ __launch_bounds__(256) void k3_adj2_aw(const float* __restrict__ adj,
                                                  const float* __restrict__ y2,
                                                  const float* __restrict__ b2,
                                                  const float* __restrict__ gamma,
                                                  const float* __restrict__ beta,
                                                  const float* __restrict__ aw,
                                                  float* __restrict__ part1) {
    __shared__ float arow[T_];
    __shared__ float red[16][H2_];
    __shared__ float xfr[H2_];
    int t = blockIdx.x, tid = threadIdx.x;
    for (int u = tid; u < T_; u += 256) arow[u] = adj[t * T_ + u];
    __syncthreads();
    int c2 = tid & 15, kg = tid >> 4;
    float acc = 0.f;
#pragma unroll 4
    for (int u = kg; u < T_; u += 16) acc += arow[u] * y2[u * H2_ + c2];
    red[kg][c2] = acc;
    __syncthreads();
    if (tid < H2_) {
        float a = 0.f;
#pragma unroll
        for (int s = 0; s < 16; ++s) a += red[s][tid];
        xfr[tid] = lrelu((a + b2[tid]) * gamma[t] + beta[t]);
    }
    __syncthreads();
    float acc0 = 0.f, acc1 = 0.f;
#pragma unroll
    for (int c = 0; c < H2_; ++c) {
        float xv = xfr[c];
        const float* awr = aw + (t * H2_ + c) * T_;
        acc0 += xv * awr[tid];
        if (tid < T_ - 256) acc1 += xv * awr[256 + tid];
    }
    part1[t * T_ + tid] = acc0;
    if (tid < T_ - 256) part1[t * T_ + 256 + tid] = acc1;
}

__global__ __launch_bounds__(256) void k4_logits_part(const float* __restrict__ dloc,
                                                      const float* __restrict__ av,
                                                      const float* __restrict__ part1,
                                                      float* __restrict__ part2) {
    int r = blockIdx.x;
    int jb = blockIdx.y & 1, q = blockIdx.y >> 1;
    __shared__ float drow[125];
    int tid = threadIdx.x;
    int t0 = q * 125;
    if (tid < 125) drow[tid] = dloc[r * T_ + t0 + tid];
    __syncthreads();
    if (tid >= 250) return;
    int j = jb * 250 + tid;
    float acc = 0.f;
#pragma unroll 5
    for (int i = 0; i < 125; ++i) {
        int t = t0 + i;
        acc += drow[i] * av[t * T_ + j] + part1[t * T_ + j];
    }
    part2[q * (R_ * T_) + r * T_ + j] = acc;
}

__global__ __launch_bounds__(256) void k4_reduce_exp(const float* __restrict__ part2,
                                                     float* __restrict__ elog) {
    int gid = blockIdx.x * 256 + threadIdx.x;
    if (gid >= R_ * T_) return;
    float v = part2[gid] + part2[R_ * T_ + gid] +
              part2[2 * R_ * T_ + gid] + part2[3 * R_ * T_ + gid];
    elog[gid] = __expf(v);
}

// ---------------- k7: ring-2 DMA pipeline, counted vmcnt ----------------
typedef const char __attribute__((address_space(1)))* gas_p;
typedef char __attribute__((address_space(3)))* las_p;

// slot = (r, chunk): wave owns rows q*50+r for q in [chunk*8, chunk*8+8).
// elog[r] lives in registers for all 8 rows. Rows staged 2-per-group into a
// 2-buffer LDS ring via global_load_lds; counted vmcnt waits keep 4-8 loads
// in flight during every compute phase (never drain to 0 mid-kernel).
__global__ __launch_bounds__(256) void k7_softmax(const float* __restrict__ gu,
                                                  const float4* __restrict__ elog,
                                                  float4* __restrict__ out) {
    __shared__ char sm[4][2][2][2000];   // [wave][buf][rowInGroup][bytes] = 32000
    int tid = threadIdx.x;
    int wave = tid >> 6, lane = tid & 63;
    int slot = blockIdx.x * 4 + wave;
    if (slot >= NSLOT_) return;
    int r = slot % R_;
    int chunk = slot / R_;
    int q0 = chunk * 8;
    bool has1 = lane < 61;
    int iA = lane, iB = has1 ? 64 + lane : lane;

    // elog row r -> registers (2 loads; drained by first counted wait)
    const float4* ep = elog + r * 125;
    float4 e0 = ep[iA];
    float4 e1 = ep[iB];

    const char* gbase = (const char*)gu;
    char* smw = &sm[wave][0][0][0];

#define STAGE(BUF, G)                                                          \
    do {                                                                       \
        _Pragma("unroll")                                                      \
        for (int k = 0; k < 2; ++k) {                                          \
            int q = q0 + 2 * (G) + k;                                          \
            size_t goff = ((size_t)q * R_ + r) * 2000;                         \
            char* l = smw + ((BUF) * 2 + k) * 2000;                            \
            __builtin_amdgcn_global_load_lds((gas_p)(gbase + goff) + lane * 16,\
                                             (las_p)l, 16, 0, 0);              \
            if (has1)                                                          \
                __builtin_amdgcn_global_load_lds(                              \
                    (gas_p)(gbase + goff + 1024) + lane * 16,                  \
                    (las_p)(l + 1024), 16, 0, 0);                              \
        }                                                                      \
    } while (0)

#define PROC(BUF, G)                                                           \
    do {                                                                       \
        _Pragma("unroll")                                                      \
        for (int k = 0; k < 2; ++k) {                                          \
            int q = q0 + 2 * (G) + k;                                          \
            const float4* lrow = (const float4*)(smw + ((BUF) * 2 + k) * 2000);\
            float4 g0 = lrow[iA];                                              \
            float4 g1 = lrow[iB];                                              \
            float p0 = e0.x * __builtin_amdgcn_rcpf(-__log2f(g0.x));           \
            float p1 = e0.y * __builtin_amdgcn_rcpf(-__log2f(g0.y));           \
            float p2 = e0.z * __builtin_amdgcn_rcpf(-__log2f(g0.z));           \
            float p3 = e0.w * __builtin_amdgcn_rcpf(-__log2f(g0.w));           \
            float p4 = 0.f, p5 = 0.f, p6 = 0.f, p7 = 0.f;                      \
            if (has1) {                                                        \
                p4 = e1.x * __builtin_amdgcn_rcpf(-__log2f(g1.x));             \
                p5 = e1.y * __builtin_amdgcn_rcpf(-__log2f(g1.y));             \
                p6 = e1.z * __builtin_amdgcn_rcpf(-__log2f(g1.z));             \
                p7 = e1.w * __builtin_amdgcn_rcpf(-__log2f(g1.w));             \
            }                                                                  \
            float s = ((p0 + p1) + (p2 + p3)) + ((p4 + p5) + (p6 + p7));       \
            float tot = wave_sum_dpp(s);                                       \
            float inv = __builtin_amdgcn_rcpf(tot);                            \
            float4* orow = out + ((size_t)q * R_ + r) * 125;                   \
            float4 o0 = {p0 * inv, p1 * inv, p2 * inv, p3 * inv};              \
            orow[iA] = o0;                                                     \
            if (has1) {                                                        \
                float4 o1 = {p4 * inv, p5 * inv, p6 * inv, p7 * inv};          \
                orow[64 + lane] = o1;                                          \
            }                                                                  \
        }                                                                      \
    } while (0)

    STAGE(0, 0);                                       // +4 vmem
    STAGE(1, 1);                                       // +4
    asm volatile("s_waitcnt vmcnt(4)" ::: "memory");   // e(2)+g0(4) done; g1 in flight
    PROC(0, 0);                                        // +4 stores
    STAGE(0, 2);                                       // +4
    asm volatile("s_waitcnt vmcnt(8)" ::: "memory");   // g1 done; S0+g2 in flight
    PROC(1, 1);                                        // +4 stores
    STAGE(1, 3);                                       // +4
    asm volatile("s_waitcnt vmcnt(8)" ::: "memory");   // g2 done; S1+g3 in flight
    PROC(0, 2);                                        // +4 stores
    asm volatile("s_waitcnt vmcnt(4)" ::: "memory");   // g3 done; S2 in flight
    PROC(1, 3);
#undef STAGE
#undef PROC
}

extern "C" void kernel_launch(void* const* d_in, const int* in_sizes, int n_in,
                              void* d_out, int out_size, void* d_ws, size_t ws_size,
                              hipStream_t stream) {
    const float* state  = (const float*)d_in[0];
    const float* dloc   = (const float*)d_in[1];
    const float* noise  = (const float*)d_in[2];
    const float* gu     = (const float*)d_in[3];
    const float* payoff = (const float*)d_in[4];
    const float* adj    = (const float*)d_in[5];
    const float* g1w    = (const float*)d_in[6];
    const float* g1b    = (const float*)d_in[7];
    const float* g2w    = (const float*)d_in[8];
    const float* g2b    = (const float*)d_in[9];
    const float* gamma  = (const float*)d_in[10];
    const float* beta   = (const float*)d_in[11];
    const float* aw     = (const float*)d_in[12];
    const float* av     = (const float*)d_in[13];
    float* out = (float*)d_out;

    float* ws     = (float*)d_ws;
    float* y1     = ws;           // 16000
    float* y2     = ws + 16000;   // 8000
    float* part1  = ws + 24000;   // 250000
    float* part2  = ws + 274000;  // 100000
    float* elog   = ws + 374000;  // 25000

    k1_xw<<<T_, 256, 0, stream>>>(state, payoff, noise, g1w, y1);
    k2_adj_fused<<<T_, 256, 0, stream>>>(adj, y1, g1b, gamma, beta, g2w, y2);
    k3_adj2_aw<<<T_, 256, 0, stream>>>(adj, y2, g2b, gamma, beta, aw, part1);
    k4_logits_part<<<dim3(R_, 8), 256, 0, stream>>>(dloc, av, part1, part2);
    k4_reduce_exp<<<(R_ * T_ + 255) / 256, 256, 0, stream>>>(part2, elog);
    k7_softmax<<<(NSLOT_ + 3) / 4, 256, 0, stream>>>(
        gu, (const float4*)elog, (float4*)out);
}